// Round 5
// baseline (205.448 us; speedup 1.0000x reference)
//
#include <hip/hip_runtime.h>

// embeddings [B=2][F=32][N=2359296] f32, labels [B][N] i32, prototypes [12][32] f32
// sums[c][f] = sum_n onehot[c][n] * emb[f][n]  ==  mfma(A=onehot, B=emb)
// mfma_f32_16x16x32_bf16 layout: lane l holds outdim=l&15, k=8*(l>>4)+j (j=0..7);
// C/D: col=l&15, row=(l>>4)*4+reg.
// Sum over voxels is order-invariant -> we may assign ANY voxel to any k-slot as
// long as A (labels) and B (emb) agree. We use that to give each lane 64B
// CONTIGUOUS per feature per fused-2-K-step superstep (bigger DRAM bursts).
#define B_        2
#define F_        32
#define C_        12
#define NVOX      2359296L
#define THREADS   256
#define WAVE_SPAN 576                  // voxels per wave
#define BLOCK_SPAN (WAVE_SPAN * 4)     // 2304
#define NBLK      1024                 // grid x; 2048 total blocks = 2 exact rounds @4/CU
#define NSUPER    9                    // supersteps (64 voxels each) per wave
#define NREP      16                   // replicated global accumulators

typedef __attribute__((ext_vector_type(8))) short short8;   // 8 bf16 (4 VGPRs)
typedef __attribute__((ext_vector_type(4))) float f32x4;

union ABu { short8 s; __bf16 h[8]; unsigned u[4]; };

__device__ __forceinline__ void build_onehot(ABu& a, const int4& La, const int4& Lb, int r) {
    unsigned m0 = (min(La.x, 11) == r) ? 0x3F80u : 0u;
    unsigned m1 = (min(La.y, 11) == r) ? 0x3F80u : 0u;
    unsigned m2 = (min(La.z, 11) == r) ? 0x3F80u : 0u;
    unsigned m3 = (min(La.w, 11) == r) ? 0x3F80u : 0u;
    unsigned m4 = (min(Lb.x, 11) == r) ? 0x3F80u : 0u;
    unsigned m5 = (min(Lb.y, 11) == r) ? 0x3F80u : 0u;
    unsigned m6 = (min(Lb.z, 11) == r) ? 0x3F80u : 0u;
    unsigned m7 = (min(Lb.w, 11) == r) ? 0x3F80u : 0u;
    a.u[0] = m0 | (m1 << 16);
    a.u[1] = m2 | (m3 << 16);
    a.u[2] = m4 | (m5 << 16);
    a.u[3] = m6 | (m7 << 16);
}

__device__ __forceinline__ void cvt_frag(ABu& d, const float4& p, const float4& q) {
    d.h[0] = (__bf16)p.x; d.h[1] = (__bf16)p.y; d.h[2] = (__bf16)p.z; d.h[3] = (__bf16)p.w;
    d.h[4] = (__bf16)q.x; d.h[5] = (__bf16)q.y; d.h[6] = (__bf16)q.z; d.h[7] = (__bf16)q.w;
}

__global__ __launch_bounds__(THREADS, 4)   // 4 waves/EU -> 16 waves/CU, VGPR<=128
void accum_mfma(const float* __restrict__ emb,
                const int*   __restrict__ labels,
                float*       __restrict__ g_sums,   // [NREP][B][C*F]
                float*       __restrict__ g_cnts) { // [NREP][B][C]
    const int b    = blockIdx.y;
    const int tid  = threadIdx.x;
    const int wv   = tid >> 6;
    const int lane = tid & 63;
    const int fcol = lane & 15;        // feature col (and one-hot class row)
    const int kgrp = lane >> 4;        // 0..3
    const int rep  = blockIdx.x & (NREP - 1);

    // lane's contiguous 16-voxel run per superstep starts at n0 + t*64
    const long n0 = (long)blockIdx.x * BLOCK_SPAN + (long)wv * WAVE_SPAN + (kgrp << 4);

    const int*   lab = labels + (long)b * NVOX + n0;
    const float* e0  = emb + (long)(b * F_ + fcol) * NVOX + n0;   // features 0..15
    const float* e1  = e0 + 16L * NVOX;                           // features 16..31

    ABu ones;
#pragma unroll
    for (int p = 0; p < 4; ++p) ones.u[p] = 0x3F803F80u;          // bf16 1.0 pairs

    f32x4 acc0 = {0.f, 0.f, 0.f, 0.f};   // sums, features 0..15
    f32x4 acc1 = {0.f, 0.f, 0.f, 0.f};   // sums, features 16..31
    f32x4 acc2 = {0.f, 0.f, 0.f, 0.f};   // counts

#pragma unroll 3
    for (int t = 0; t < NSUPER; ++t) {
        // 64B-contiguous per-lane loads: 16 labels + 16 voxels of two features
        int4   L[4];
        float4 x0[4], x1[4];
#pragma unroll
        for (int r = 0; r < 4; ++r) L[r]  = *(const int4*)(lab + 4 * r);
#pragma unroll
        for (int r = 0; r < 4; ++r) x0[r] = *(const float4*)(e0 + 4 * r);
#pragma unroll
        for (int r = 0; r < 4; ++r) x1[r] = *(const float4*)(e1 + 4 * r);

        // ---- K-step A: lane's voxels 0..7 (L[0],L[1]; x?[0],x?[1]) ----
        ABu a, b0, b1;
        build_onehot(a, L[0], L[1], fcol);
        cvt_frag(b0, x0[0], x0[1]);
        cvt_frag(b1, x1[0], x1[1]);
        acc0 = __builtin_amdgcn_mfma_f32_16x16x32_bf16(a.s, b0.s,   acc0, 0, 0, 0);
        acc1 = __builtin_amdgcn_mfma_f32_16x16x32_bf16(a.s, b1.s,   acc1, 0, 0, 0);
        acc2 = __builtin_amdgcn_mfma_f32_16x16x32_bf16(a.s, ones.s, acc2, 0, 0, 0);

        // ---- K-step B: lane's voxels 8..15 (L[2],L[3]; x?[2],x?[3]) ----
        build_onehot(a, L[2], L[3], fcol);
        cvt_frag(b0, x0[2], x0[3]);
        cvt_frag(b1, x1[2], x1[3]);
        acc0 = __builtin_amdgcn_mfma_f32_16x16x32_bf16(a.s, b0.s,   acc0, 0, 0, 0);
        acc1 = __builtin_amdgcn_mfma_f32_16x16x32_bf16(a.s, b1.s,   acc1, 0, 0, 0);
        acc2 = __builtin_amdgcn_mfma_f32_16x16x32_bf16(a.s, ones.s, acc2, 0, 0, 0);

        lab += 64; e0 += 64; e1 += 64;
    }

    // ---- block reduction: LDS atomics (distinct addresses within a wave) ----
    __shared__ float lsum[16 * 32];
    __shared__ float lcnt[16];
    for (int i = tid; i < 16 * 32; i += THREADS) lsum[i] = 0.f;
    if (tid < 16) lcnt[tid] = 0.f;
    __syncthreads();

#pragma unroll
    for (int r = 0; r < 4; ++r) {
        const int c = (kgrp << 2) + r;          // D row = class
        atomicAdd(&lsum[c * 32 + fcol],      acc0[r]);
        atomicAdd(&lsum[c * 32 + 16 + fcol], acc1[r]);
    }
    if (fcol == 0) {
#pragma unroll
        for (int r = 0; r < 4; ++r) atomicAdd(&lcnt[(kgrp << 2) + r], acc2[r]);
    }
    __syncthreads();

    // flush to replicated global accumulators
    float* gs = g_sums + ((long)rep * B_ + b) * (C_ * F_);
    float* gc = g_cnts + ((long)rep * B_ + b) * C_;
    for (int i = tid; i < C_ * F_; i += THREADS)
        atomicAdd(&gs[i], lsum[i]);
    if (tid < C_)
        atomicAdd(&gc[tid], lcnt[tid]);
}

__global__ void finalize_kernel(const float* __restrict__ g_sums,
                                const float* __restrict__ g_cnts,
                                const float* __restrict__ proto,
                                float*       __restrict__ out) {
    const int idx = threadIdx.x;               // 0..383 = c*F + f
    if (idx >= C_ * F_) return;
    const int c = idx / F_;
    float p = proto[idx];
#pragma unroll
    for (int b = 0; b < B_; ++b) {
        float cnt = 0.f, s = 0.f;
#pragma unroll
        for (int rep = 0; rep < NREP; ++rep) {
            s   += g_sums[((long)rep * B_ + b) * (C_ * F_) + idx];
            cnt += g_cnts[((long)rep * B_ + b) * C_ + c];
        }
        if (cnt > 0.f) p = 0.9f * p + 0.1f * (s / cnt);
    }
    out[idx] = p;
}

extern "C" void kernel_launch(void* const* d_in, const int* in_sizes, int n_in,
                              void* d_out, int out_size, void* d_ws, size_t ws_size,
                              hipStream_t stream) {
    const float* emb    = (const float*)d_in[0];
    const int*   labels = (const int*)d_in[1];
    const float* proto  = (const float*)d_in[2];
    float*       out    = (float*)d_out;

    float* g_sums = (float*)d_ws;                      // NREP*B*C*F floats
    float* g_cnts = g_sums + NREP * B_ * C_ * F_;      // NREP*B*C floats

    hipMemsetAsync(d_ws, 0,
                   (size_t)(NREP * B_ * (C_ * F_ + C_)) * sizeof(float), stream);

    dim3 grid(NBLK, B_);
    accum_mfma<<<grid, THREADS, 0, stream>>>(emb, labels, g_sums, g_cnts);
    finalize_kernel<<<1, C_ * F_, 0, stream>>>(g_sums, g_cnts, proto, out);
}

// Round 7
// 158.310 us; speedup vs baseline: 1.2978x; 1.2978x over previous
//
#include <hip/hip_runtime.h>

// embeddings [B=2][F=32][N=2359296] f32, labels [B][N] i32, prototypes [12][32] f32
// sums[c][f] = sum_n onehot[c][n] * emb[f][n]  ==  mfma(A=onehot, B=emb)
// mfma_f32_16x16x32_bf16 layout: lane l holds outdim=l&15, k=8*(l>>4)+j (j=0..7);
// C/D: col=l&15, row=(l>>4)*4+reg.
// R5 lesson: 12-load superstep x unroll3 under a 128-VGPR cap spilled to scratch
// (124->205us). This is R4's light body (6 loads/K-step) + occupancy bound.
// R6 fix: __builtin_nontemporal_load needs ext_vector_type, not HIP float4/int4.
#define B_        2
#define F_        32
#define C_        12
#define NVOX      2359296L
#define THREADS   256
#define WAVE_SPAN 576                  // voxels per wave
#define BLOCK_SPAN (WAVE_SPAN * 4)     // 2304
#define NBLK      1024                 // 2048 total blocks
#define KSTEPS    (WAVE_SPAN / 32)     // 18 mfma K-steps per wave
#define NREP      16                   // replicated global accumulators

typedef __attribute__((ext_vector_type(8))) short short8;   // 8 bf16 (4 VGPRs)
typedef __attribute__((ext_vector_type(4))) float f32x4;
typedef __attribute__((ext_vector_type(4))) float fvec4;    // loadable vector
typedef __attribute__((ext_vector_type(4))) int   ivec4;

union ABu { short8 s; __bf16 h[8]; unsigned u[4]; };

__device__ __forceinline__ fvec4 nt_load_f4(const float* p) {
    return __builtin_nontemporal_load((const fvec4*)p);
}
__device__ __forceinline__ ivec4 nt_load_i4(const int* p) {
    return __builtin_nontemporal_load((const ivec4*)p);
}

__global__ __launch_bounds__(THREADS, 4)   // 4 waves/EU min -> VGPR<=128, 16 waves/CU
void accum_mfma(const float* __restrict__ emb,
                const int*   __restrict__ labels,
                float*       __restrict__ g_sums,   // [NREP][B][C*F]
                float*       __restrict__ g_cnts) { // [NREP][B][C]
    const int b    = blockIdx.y;
    const int tid  = threadIdx.x;
    const int wv   = tid >> 6;
    const int lane = tid & 63;
    const int fcol = lane & 15;        // feature col (and one-hot class row)
    const int kgrp = lane >> 4;        // 0..3, k-base = kgrp*8
    const int rep  = blockIdx.x & (NREP - 1);

    const long n0 = (long)blockIdx.x * BLOCK_SPAN + (long)wv * WAVE_SPAN + (kgrp << 3);

    const int*   lab = labels + (long)b * NVOX + n0;
    const float* e0  = emb + (long)(b * F_ + fcol) * NVOX + n0;   // features 0..15
    const float* e1  = e0 + 16L * NVOX;                           // features 16..31

    ABu ones;
#pragma unroll
    for (int p = 0; p < 4; ++p) ones.u[p] = 0x3F803F80u;          // bf16 1.0 pairs

    f32x4 acc0 = {0.f, 0.f, 0.f, 0.f};   // sums, features 0..15
    f32x4 acc1 = {0.f, 0.f, 0.f, 0.f};   // sums, features 16..31
    f32x4 acc2 = {0.f, 0.f, 0.f, 0.f};   // counts

#pragma unroll 2
    for (int s = 0; s < KSTEPS; ++s) {
        // 8 labels for this lane's k-slots (16-lane groups share -> one transaction)
        ivec4 L0 = nt_load_i4(lab);
        ivec4 L1 = nt_load_i4(lab + 4);
        // 8 consecutive voxels of this lane's two features
        fvec4 v00 = nt_load_f4(e0);
        fvec4 v01 = nt_load_f4(e0 + 4);
        fvec4 v10 = nt_load_f4(e1);
        fvec4 v11 = nt_load_f4(e1 + 4);

        // A fragment: onehot[row=fcol][k] as bf16 {0,1}
        ABu a;
        {
            const int r = fcol;
            unsigned m0 = (min(L0.x, 11) == r) ? 0x3F80u : 0u;
            unsigned m1 = (min(L0.y, 11) == r) ? 0x3F80u : 0u;
            unsigned m2 = (min(L0.z, 11) == r) ? 0x3F80u : 0u;
            unsigned m3 = (min(L0.w, 11) == r) ? 0x3F80u : 0u;
            unsigned m4 = (min(L1.x, 11) == r) ? 0x3F80u : 0u;
            unsigned m5 = (min(L1.y, 11) == r) ? 0x3F80u : 0u;
            unsigned m6 = (min(L1.z, 11) == r) ? 0x3F80u : 0u;
            unsigned m7 = (min(L1.w, 11) == r) ? 0x3F80u : 0u;
            a.u[0] = m0 | (m1 << 16);
            a.u[1] = m2 | (m3 << 16);
            a.u[2] = m4 | (m5 << 16);
            a.u[3] = m6 | (m7 << 16);
        }

        // B fragments: emb cast to bf16 (RNE via v_cvt_pk_bf16_f32)
        ABu b0, b1;
        b0.h[0] = (__bf16)v00.x; b0.h[1] = (__bf16)v00.y;
        b0.h[2] = (__bf16)v00.z; b0.h[3] = (__bf16)v00.w;
        b0.h[4] = (__bf16)v01.x; b0.h[5] = (__bf16)v01.y;
        b0.h[6] = (__bf16)v01.z; b0.h[7] = (__bf16)v01.w;
        b1.h[0] = (__bf16)v10.x; b1.h[1] = (__bf16)v10.y;
        b1.h[2] = (__bf16)v10.z; b1.h[3] = (__bf16)v10.w;
        b1.h[4] = (__bf16)v11.x; b1.h[5] = (__bf16)v11.y;
        b1.h[6] = (__bf16)v11.z; b1.h[7] = (__bf16)v11.w;

        acc0 = __builtin_amdgcn_mfma_f32_16x16x32_bf16(a.s, b0.s,   acc0, 0, 0, 0);
        acc1 = __builtin_amdgcn_mfma_f32_16x16x32_bf16(a.s, b1.s,   acc1, 0, 0, 0);
        acc2 = __builtin_amdgcn_mfma_f32_16x16x32_bf16(a.s, ones.s, acc2, 0, 0, 0);

        lab += 32; e0 += 32; e1 += 32;
    }

    // ---- block reduction: LDS atomics (distinct addresses within a wave) ----
    __shared__ float lsum[16 * 32];
    __shared__ float lcnt[16];
    for (int i = tid; i < 16 * 32; i += THREADS) lsum[i] = 0.f;
    if (tid < 16) lcnt[tid] = 0.f;
    __syncthreads();

#pragma unroll
    for (int r = 0; r < 4; ++r) {
        const int c = (kgrp << 2) + r;          // D row = class
        atomicAdd(&lsum[c * 32 + fcol],      acc0[r]);
        atomicAdd(&lsum[c * 32 + 16 + fcol], acc1[r]);
    }
    if (fcol == 0) {
#pragma unroll
        for (int r = 0; r < 4; ++r) atomicAdd(&lcnt[(kgrp << 2) + r], acc2[r]);
    }
    __syncthreads();

    // flush to replicated global accumulators (rep = blockIdx.x & 15)
    float* gs = g_sums + ((long)rep * B_ + b) * (C_ * F_);
    float* gc = g_cnts + ((long)rep * B_ + b) * C_;
    for (int i = tid; i < C_ * F_; i += THREADS)
        atomicAdd(&gs[i], lsum[i]);
    if (tid < C_)
        atomicAdd(&gc[tid], lcnt[tid]);
}

__global__ void finalize_kernel(const float* __restrict__ g_sums,
                                const float* __restrict__ g_cnts,
                                const float* __restrict__ proto,
                                float*       __restrict__ out) {
    const int idx = threadIdx.x;               // 0..383 = c*F + f
    if (idx >= C_ * F_) return;
    const int c = idx / F_;
    float p = proto[idx];
#pragma unroll
    for (int b = 0; b < B_; ++b) {
        float cnt = 0.f, s = 0.f;
#pragma unroll
        for (int rep = 0; rep < NREP; ++rep) {
            s   += g_sums[((long)rep * B_ + b) * (C_ * F_) + idx];
            cnt += g_cnts[((long)rep * B_ + b) * C_ + c];
        }
        if (cnt > 0.f) p = 0.9f * p + 0.1f * (s / cnt);
    }
    out[idx] = p;
}

extern "C" void kernel_launch(void* const* d_in, const int* in_sizes, int n_in,
                              void* d_out, int out_size, void* d_ws, size_t ws_size,
                              hipStream_t stream) {
    const float* emb    = (const float*)d_in[0];
    const int*   labels = (const int*)d_in[1];
    const float* proto  = (const float*)d_in[2];
    float*       out    = (float*)d_out;

    float* g_sums = (float*)d_ws;                      // NREP*B*C*F floats
    float* g_cnts = g_sums + NREP * B_ * C_ * F_;      // NREP*B*C floats

    (void)hipMemsetAsync(d_ws, 0,
                   (size_t)(NREP * B_ * (C_ * F_ + C_)) * sizeof(float), stream);

    dim3 grid(NBLK, B_);
    accum_mfma<<<grid, THREADS, 0, stream>>>(emb, labels, g_sums, g_cnts);
    finalize_kernel<<<1, C_ * F_, 0, stream>>>(g_sums, g_cnts, proto, out);
}

// Round 8
// 124.214 us; speedup vs baseline: 1.6540x; 1.2745x over previous
//
#include <hip/hip_runtime.h>

// embeddings [B=2][F=32][N=2359296] f32, labels [B][N] i32, prototypes [12][32] f32
// sums[c][f] = sum_n onehot[c][n] * emb[f][n]  ==  mfma(A=onehot, B=emb)
// mfma_f32_16x16x32_bf16 layout: lane l holds outdim=l&15, k=8*(l>>4)+j (j=0..7);
// C/D: col=l&15, row=(l>>4)*4+reg.
// R5 lesson: 12-load superstep x unroll3 under 128-VGPR cap spilled (124->205us).
// R7 lesson: nontemporal loads broke L2 sector-merging of the 128B/feature line
//            shared by 8 lane-requests per K-step (124->158us). Plain loads here.
// This round: R4 body exactly + __launch_bounds__(256,4) only (occupancy probe).
#define B_        2
#define F_        32
#define C_        12
#define NVOX      2359296L
#define THREADS   256
#define WAVE_SPAN 576                  // voxels per wave
#define BLOCK_SPAN (WAVE_SPAN * 4)     // 2304
#define NBLK      1024                 // 2048 total blocks
#define KSTEPS    (WAVE_SPAN / 32)     // 18 mfma K-steps per wave
#define NREP      16                   // replicated global accumulators

typedef __attribute__((ext_vector_type(8))) short short8;   // 8 bf16 (4 VGPRs)
typedef __attribute__((ext_vector_type(4))) float f32x4;

union ABu { short8 s; __bf16 h[8]; unsigned u[4]; };

__global__ __launch_bounds__(THREADS, 4)   // min 4 waves/EU -> VGPR<=128, 16 waves/CU
void accum_mfma(const float* __restrict__ emb,
                const int*   __restrict__ labels,
                float*       __restrict__ g_sums,   // [NREP][B][C*F]
                float*       __restrict__ g_cnts) { // [NREP][B][C]
    const int b    = blockIdx.y;
    const int tid  = threadIdx.x;
    const int wv   = tid >> 6;
    const int lane = tid & 63;
    const int fcol = lane & 15;        // feature col (and one-hot class row)
    const int kgrp = lane >> 4;        // 0..3, k-base = kgrp*8
    const int rep  = blockIdx.x & (NREP - 1);

    const long n0 = (long)blockIdx.x * BLOCK_SPAN + (long)wv * WAVE_SPAN + (kgrp << 3);

    const int*   lab = labels + (long)b * NVOX + n0;
    const float* e0  = emb + (long)(b * F_ + fcol) * NVOX + n0;   // features 0..15
    const float* e1  = e0 + 16L * NVOX;                           // features 16..31

    ABu ones;
#pragma unroll
    for (int p = 0; p < 4; ++p) ones.u[p] = 0x3F803F80u;          // bf16 1.0 pairs

    f32x4 acc0 = {0.f, 0.f, 0.f, 0.f};   // sums, features 0..15
    f32x4 acc1 = {0.f, 0.f, 0.f, 0.f};   // sums, features 16..31
    f32x4 acc2 = {0.f, 0.f, 0.f, 0.f};   // counts

#pragma unroll 2
    for (int s = 0; s < KSTEPS; ++s) {
        // 8 labels for this lane's k-slots (16-lane groups share -> one transaction)
        int4 L0 = *(const int4*)(lab);
        int4 L1 = *(const int4*)(lab + 4);
        // 8 consecutive voxels of this lane's two features
        float4 v00 = *(const float4*)(e0);
        float4 v01 = *(const float4*)(e0 + 4);
        float4 v10 = *(const float4*)(e1);
        float4 v11 = *(const float4*)(e1 + 4);

        // A fragment: onehot[row=fcol][k] as bf16 {0,1}
        ABu a;
        {
            const int r = fcol;
            unsigned m0 = (min(L0.x, 11) == r) ? 0x3F80u : 0u;
            unsigned m1 = (min(L0.y, 11) == r) ? 0x3F80u : 0u;
            unsigned m2 = (min(L0.z, 11) == r) ? 0x3F80u : 0u;
            unsigned m3 = (min(L0.w, 11) == r) ? 0x3F80u : 0u;
            unsigned m4 = (min(L1.x, 11) == r) ? 0x3F80u : 0u;
            unsigned m5 = (min(L1.y, 11) == r) ? 0x3F80u : 0u;
            unsigned m6 = (min(L1.z, 11) == r) ? 0x3F80u : 0u;
            unsigned m7 = (min(L1.w, 11) == r) ? 0x3F80u : 0u;
            a.u[0] = m0 | (m1 << 16);
            a.u[1] = m2 | (m3 << 16);
            a.u[2] = m4 | (m5 << 16);
            a.u[3] = m6 | (m7 << 16);
        }

        // B fragments: emb cast to bf16 (RNE via v_cvt_pk_bf16_f32)
        ABu b0, b1;
        b0.h[0] = (__bf16)v00.x; b0.h[1] = (__bf16)v00.y;
        b0.h[2] = (__bf16)v00.z; b0.h[3] = (__bf16)v00.w;
        b0.h[4] = (__bf16)v01.x; b0.h[5] = (__bf16)v01.y;
        b0.h[6] = (__bf16)v01.z; b0.h[7] = (__bf16)v01.w;
        b1.h[0] = (__bf16)v10.x; b1.h[1] = (__bf16)v10.y;
        b1.h[2] = (__bf16)v10.z; b1.h[3] = (__bf16)v10.w;
        b1.h[4] = (__bf16)v11.x; b1.h[5] = (__bf16)v11.y;
        b1.h[6] = (__bf16)v11.z; b1.h[7] = (__bf16)v11.w;

        acc0 = __builtin_amdgcn_mfma_f32_16x16x32_bf16(a.s, b0.s,   acc0, 0, 0, 0);
        acc1 = __builtin_amdgcn_mfma_f32_16x16x32_bf16(a.s, b1.s,   acc1, 0, 0, 0);
        acc2 = __builtin_amdgcn_mfma_f32_16x16x32_bf16(a.s, ones.s, acc2, 0, 0, 0);

        lab += 32; e0 += 32; e1 += 32;
    }

    // ---- block reduction: LDS atomics (distinct addresses within a wave) ----
    __shared__ float lsum[16 * 32];
    __shared__ float lcnt[16];
    for (int i = tid; i < 16 * 32; i += THREADS) lsum[i] = 0.f;
    if (tid < 16) lcnt[tid] = 0.f;
    __syncthreads();

#pragma unroll
    for (int r = 0; r < 4; ++r) {
        const int c = (kgrp << 2) + r;          // D row = class
        atomicAdd(&lsum[c * 32 + fcol],      acc0[r]);
        atomicAdd(&lsum[c * 32 + 16 + fcol], acc1[r]);
    }
    if (fcol == 0) {
#pragma unroll
        for (int r = 0; r < 4; ++r) atomicAdd(&lcnt[(kgrp << 2) + r], acc2[r]);
    }
    __syncthreads();

    // flush to replicated global accumulators (rep = blockIdx.x & 15)
    float* gs = g_sums + ((long)rep * B_ + b) * (C_ * F_);
    float* gc = g_cnts + ((long)rep * B_ + b) * C_;
    for (int i = tid; i < C_ * F_; i += THREADS)
        atomicAdd(&gs[i], lsum[i]);
    if (tid < C_)
        atomicAdd(&gc[tid], lcnt[tid]);
}

__global__ void finalize_kernel(const float* __restrict__ g_sums,
                                const float* __restrict__ g_cnts,
                                const float* __restrict__ proto,
                                float*       __restrict__ out) {
    const int idx = threadIdx.x;               // 0..383 = c*F + f
    if (idx >= C_ * F_) return;
    const int c = idx / F_;
    float p = proto[idx];
#pragma unroll
    for (int b = 0; b < B_; ++b) {
        float cnt = 0.f, s = 0.f;
#pragma unroll
        for (int rep = 0; rep < NREP; ++rep) {
            s   += g_sums[((long)rep * B_ + b) * (C_ * F_) + idx];
            cnt += g_cnts[((long)rep * B_ + b) * C_ + c];
        }
        if (cnt > 0.f) p = 0.9f * p + 0.1f * (s / cnt);
    }
    out[idx] = p;
}

extern "C" void kernel_launch(void* const* d_in, const int* in_sizes, int n_in,
                              void* d_out, int out_size, void* d_ws, size_t ws_size,
                              hipStream_t stream) {
    const float* emb    = (const float*)d_in[0];
    const int*   labels = (const int*)d_in[1];
    const float* proto  = (const float*)d_in[2];
    float*       out    = (float*)d_out;

    float* g_sums = (float*)d_ws;                      // NREP*B*C*F floats
    float* g_cnts = g_sums + NREP * B_ * C_ * F_;      // NREP*B*C floats

    (void)hipMemsetAsync(d_ws, 0,
                   (size_t)(NREP * B_ * (C_ * F_ + C_)) * sizeof(float), stream);

    dim3 grid(NBLK, B_);
    accum_mfma<<<grid, THREADS, 0, stream>>>(emb, labels, g_sums, g_cnts);
    finalize_kernel<<<1, C_ * F_, 0, stream>>>(g_sums, g_cnts, proto, out);
}